// Round 4
// baseline (65.404 us; speedup 1.0000x reference)
//
#include <hip/hip_runtime.h>
#include <math.h>

#define UNITS  512
#define BATCH  32
#define SEQ    4096
#define CHUNKS 32
#define RPC    (SEQ / CHUNKS)   // 128 rows per chunk
#define PREPB  64               // k_prep blocks; pp partials per batch

// workspace layout (float offsets)
#define OFF_UV    0                       // 512
#define OFF_WV    512                     // 512
#define OFF_PP    1024                    // pp[b*PREPB+blk]  (32 x 64)
#define OFF_CB    3072                    // 1 scalar
#define OFF_PSUM  4096                    // BATCH*CHUNKS = 1024
#define OFF_PCTX  8192                    // BATCH*CHUNKS*UNITS = 524288 (~2 MB)

typedef float f4 __attribute__((ext_vector_type(4)));

__device__ inline f4 ld_nt(const float* p) {
    return __builtin_nontemporal_load((const f4*)p);
}

__device__ inline float wave_reduce_add(float v) {
#pragma unroll
    for (int off = 32; off >= 1; off >>= 1) v += __shfl_xor(v, off);
    return v;
}

__device__ inline float dot8(f4 a, f4 b, f4 u0, f4 u1) {
    f4 t = a * u0 + b * u1;
    return t.x + t.y + t.z + t.w;
}

// K0 (PREPB blocks x 8 rows): uv/wv rows, cb scalar, pbias partials.
__global__ __launch_bounds__(256) void k_prep(const float* __restrict__ Ww,
                                              const float* __restrict__ Uw,
                                              const float* __restrict__ Vw,
                                              const float* __restrict__ Wb,
                                              const float* __restrict__ Ub,
                                              const float* __restrict__ Vb,
                                              const float* __restrict__ s_prev,
                                              float* __restrict__ ws) {
    int tid = threadIdx.x, wave = tid >> 6, lane = tid & 63;
    f4 v0 = *(const f4*)(Vw + lane * 8);
    f4 v1 = *(const f4*)(Vw + lane * 8 + 4);
    int rowbase = blockIdx.x * 8;

    for (int i = wave; i < 8; i += 4) {
        int u = rowbase + i;
        const float* ur = Uw + (size_t)u * UNITS + lane * 8;
        f4 a = *(const f4*)ur;
        f4 b = *(const f4*)(ur + 4);
        float d = wave_reduce_add(dot8(a, b, v0, v1));
        if (lane == 0) ws[OFF_UV + u] = d;
        const float* wr = Ww + (size_t)u * UNITS + lane * 8;
        a = *(const f4*)wr;
        b = *(const f4*)(wr + 4);
        d = wave_reduce_add(dot8(a, b, v0, v1));
        if (lane == 0) ws[OFF_WV + u] = d;
    }

    if (blockIdx.x == 0) {
        float part = 0.f;
        for (int v = tid; v < UNITS; v += 256) part += (Wb[v] + Ub[v]) * Vw[v];
        part = wave_reduce_add(part);
        __shared__ float wred[4];
        if (lane == 0) wred[wave] = part;
        __syncthreads();
        if (tid == 0) ws[OFF_CB] = wred[0] + wred[1] + wred[2] + wred[3] + Vb[0];
    }

    __syncthreads();  // this block's wv rows visible block-wide

    // pp[b][blk] = sum_{j=0..7} s_prev[b, rowbase+j] * wv[rowbase+j]
    int b = tid >> 3;      // 0..31
    int g = tid & 7;       // 0..7
    int u = rowbase + g;
    float p = s_prev[(size_t)b * UNITS + u] * ws[OFF_WV + u];
    p += __shfl_xor(p, 1);
    p += __shfl_xor(p, 2);
    p += __shfl_xor(p, 4);
    if (g == 0) ws[OFF_PP + b * PREPB + blockIdx.x] = p;
}

// K1 (32x32 blocks): stream h once (NT loads). p=exp(tanh(h.uv+pb))
// unnormalized to output weights region; partial Z and context to ws.
__global__ __launch_bounds__(256) void k_main(const float* __restrict__ h,
                                              float* __restrict__ ws,
                                              float* __restrict__ out) {
    int chunk = blockIdx.x, b = blockIdx.y;
    int tid = threadIdx.x, wave = tid >> 6, lane = tid & 63;

    __shared__ float pbsh;
    {
        float p = ws[OFF_PP + b * PREPB + lane];   // PREPB == 64 lanes
        p = wave_reduce_add(p);
        if (tid == 0) pbsh = p + ws[OFF_CB];
    }
    f4 u0 = *(const f4*)(ws + OFF_UV + lane * 8);
    f4 u1 = *(const f4*)(ws + OFF_UV + lane * 8 + 4);
    __syncthreads();
    float pb = pbsh;

    f4 acc0 = {0.f, 0.f, 0.f, 0.f};
    f4 acc1 = {0.f, 0.f, 0.f, 0.f};
    float zs = 0.f;

    const float* hb = h + ((size_t)b * SEQ + (size_t)chunk * RPC) * UNITS + lane * 8;
    float* pout = out + (size_t)BATCH * UNITS + (size_t)b * SEQ + (size_t)chunk * RPC;

    for (int r = wave; r < RPC; r += 8) {
        const float* r0 = hb + (size_t)r * UNITS;
        const float* r1 = hb + (size_t)(r + 4) * UNITS;
        f4 a0 = ld_nt(r0);
        f4 b0 = ld_nt(r0 + 4);
        f4 a1 = ld_nt(r1);
        f4 b1 = ld_nt(r1 + 4);

        float d0 = dot8(a0, b0, u0, u1);
        float d1 = dot8(a1, b1, u0, u1);
#pragma unroll
        for (int off = 32; off >= 1; off >>= 1) {
            d0 += __shfl_xor(d0, off);
            d1 += __shfl_xor(d1, off);
        }
        float w0 = __expf(tanhf(d0 + pb));
        float w1 = __expf(tanhf(d1 + pb));
        if (lane == 0) { pout[r] = w0; pout[r + 4] = w1; }
        zs += w0 + w1;
        acc0 += w0 * a0 + w1 * a1;
        acc1 += w0 * b0 + w1 * b1;
    }

    __shared__ float lctx[4][UNITS];
    __shared__ float lsum[4];
    *(f4*)&lctx[wave][lane * 8]     = acc0;
    *(f4*)&lctx[wave][lane * 8 + 4] = acc1;
    if (lane == 0) lsum[wave] = zs;
    __syncthreads();

    float* pc = ws + OFF_PCTX + ((size_t)(b * CHUNKS + chunk)) * UNITS;
    for (int col = tid; col < UNITS; col += 256)
        pc[col] = lctx[0][col] + lctx[1][col] + lctx[2][col] + lctx[3][col];
    if (tid == 0)
        ws[OFF_PSUM + b * CHUNKS + chunk] = lsum[0] + lsum[1] + lsum[2] + lsum[3];
}

// K2 (256 blocks): block = (b, slice). Z from psum (redundant per block),
// context slice of 64 cols, scale 512 weights in place.
__global__ __launch_bounds__(256) void k_final(const float* __restrict__ ws,
                                               float* __restrict__ out) {
    int blk = blockIdx.x;
    int b = blk >> 3, sl = blk & 7;
    int tid = threadIdx.x;

    __shared__ float zsh;
    if (tid < 64) {
        float z = (tid < CHUNKS) ? ws[OFF_PSUM + b * CHUNKS + tid] : 0.f;
        z = wave_reduce_add(z);
        if (tid == 0) zsh = 1.0f / z;
    }
    __syncthreads();
    float rz = zsh;

    int col = sl * 64 + (tid & 63);
    int grp = tid >> 6;
    float s = 0.f;
#pragma unroll
    for (int c = 0; c < 8; ++c)
        s += ws[OFF_PCTX + (size_t)(b * CHUNKS + grp * 8 + c) * UNITS + col];
    __shared__ float red[4][64];
    red[grp][tid & 63] = s;
    __syncthreads();
    if (tid < 64)
        out[(size_t)b * UNITS + sl * 64 + tid] =
            (red[0][tid] + red[1][tid] + red[2][tid] + red[3][tid]) * rz;

    float* wout = out + (size_t)BATCH * UNITS + (size_t)b * SEQ + sl * 512;
#pragma unroll
    for (int i = tid; i < 512; i += 256) wout[i] *= rz;
}

extern "C" void kernel_launch(void* const* d_in, const int* in_sizes, int n_in,
                              void* d_out, int out_size, void* d_ws, size_t ws_size,
                              hipStream_t stream) {
    (void)in_sizes; (void)n_in; (void)out_size; (void)ws_size;
    const float* s_prev = (const float*)d_in[0];
    const float* h      = (const float*)d_in[1];
    const float* Ww     = (const float*)d_in[2];
    const float* Wb     = (const float*)d_in[3];
    const float* Uw     = (const float*)d_in[4];
    const float* Ub     = (const float*)d_in[5];
    const float* Vw     = (const float*)d_in[6];
    const float* Vb     = (const float*)d_in[7];
    float* out = (float*)d_out;
    float* ws  = (float*)d_ws;

    hipLaunchKernelGGL(k_prep,  dim3(PREPB),         dim3(256), 0, stream,
                       Ww, Uw, Vw, Wb, Ub, Vb, s_prev, ws);
    hipLaunchKernelGGL(k_main,  dim3(CHUNKS, BATCH), dim3(256), 0, stream,
                       h, ws, out);
    hipLaunchKernelGGL(k_final, dim3(256),           dim3(256), 0, stream,
                       ws, out);
}

// Round 5
// 54.608 us; speedup vs baseline: 1.1977x; 1.1977x over previous
//
#include <hip/hip_runtime.h>
#include <math.h>

#define UNITS  512
#define BATCH  32
#define SEQ    4096
#define CHUNKS 32
#define RPC    (SEQ / CHUNKS)   // 128 rows per chunk
#define PREPB  64               // k_prep blocks; pp partials per batch

// workspace layout (float offsets)
#define OFF_UV    0                       // 512
#define OFF_WV    512                     // 512
#define OFF_PP    1024                    // pp[b*PREPB+blk]  (32 x 64)
#define OFF_CB    3072                    // 1 scalar
#define OFF_PSUM  4096                    // BATCH*CHUNKS = 1024
#define OFF_PCTX  8192                    // BATCH*CHUNKS*UNITS = 524288 (~2 MB)

typedef float f4 __attribute__((ext_vector_type(4)));

__device__ inline float wave_reduce_add(float v) {
#pragma unroll
    for (int off = 32; off >= 1; off >>= 1) v += __shfl_xor(v, off);
    return v;
}

__device__ inline float dot8(f4 a, f4 b, f4 u0, f4 u1) {
    f4 t = a * u0 + b * u1;
    return t.x + t.y + t.z + t.w;
}

// K0 (PREPB blocks x 8 rows): uv/wv rows, cb scalar, pbias partials.
__global__ __launch_bounds__(256) void k_prep(const float* __restrict__ Ww,
                                              const float* __restrict__ Uw,
                                              const float* __restrict__ Vw,
                                              const float* __restrict__ Wb,
                                              const float* __restrict__ Ub,
                                              const float* __restrict__ Vb,
                                              const float* __restrict__ s_prev,
                                              float* __restrict__ ws) {
    int tid = threadIdx.x, wave = tid >> 6, lane = tid & 63;
    f4 v0 = *(const f4*)(Vw + lane * 8);
    f4 v1 = *(const f4*)(Vw + lane * 8 + 4);
    int rowbase = blockIdx.x * 8;

    for (int i = wave; i < 8; i += 4) {
        int u = rowbase + i;
        const float* ur = Uw + (size_t)u * UNITS + lane * 8;
        f4 a = *(const f4*)ur;
        f4 b = *(const f4*)(ur + 4);
        float d = wave_reduce_add(dot8(a, b, v0, v1));
        if (lane == 0) ws[OFF_UV + u] = d;
        const float* wr = Ww + (size_t)u * UNITS + lane * 8;
        a = *(const f4*)wr;
        b = *(const f4*)(wr + 4);
        d = wave_reduce_add(dot8(a, b, v0, v1));
        if (lane == 0) ws[OFF_WV + u] = d;
    }

    if (blockIdx.x == 0) {
        float part = 0.f;
        for (int v = tid; v < UNITS; v += 256) part += (Wb[v] + Ub[v]) * Vw[v];
        part = wave_reduce_add(part);
        __shared__ float wred[4];
        if (lane == 0) wred[wave] = part;
        __syncthreads();
        if (tid == 0) ws[OFF_CB] = wred[0] + wred[1] + wred[2] + wred[3] + Vb[0];
    }

    __syncthreads();  // this block's wv rows visible block-wide

    // pp[b][blk] = sum_{j=0..7} s_prev[b, rowbase+j] * wv[rowbase+j]
    int b = tid >> 3;      // 0..31
    int g = tid & 7;       // 0..7
    int u = rowbase + g;
    float p = s_prev[(size_t)b * UNITS + u] * ws[OFF_WV + u];
    p += __shfl_xor(p, 1);
    p += __shfl_xor(p, 2);
    p += __shfl_xor(p, 4);
    if (g == 0) ws[OFF_PP + b * PREPB + blockIdx.x] = p;
}

// K1 (32x32 blocks): stream h once, 4 rows in flight per wave.
// p=exp(tanh(h.uv+pb)) unnormalized to output weights region; partial Z
// and context to ws.
__global__ __launch_bounds__(256) void k_main(const float* __restrict__ h,
                                              float* __restrict__ ws,
                                              float* __restrict__ out) {
    int chunk = blockIdx.x, b = blockIdx.y;
    int tid = threadIdx.x, wave = tid >> 6, lane = tid & 63;

    __shared__ float pbsh;
    {
        float p = ws[OFF_PP + b * PREPB + lane];   // PREPB == 64 lanes
        p = wave_reduce_add(p);
        if (tid == 0) pbsh = p + ws[OFF_CB];
    }
    f4 u0 = *(const f4*)(ws + OFF_UV + lane * 8);
    f4 u1 = *(const f4*)(ws + OFF_UV + lane * 8 + 4);
    __syncthreads();
    float pb = pbsh;

    f4 acc0 = {0.f, 0.f, 0.f, 0.f};
    f4 acc1 = {0.f, 0.f, 0.f, 0.f};
    float zs = 0.f;

    const float* hb = h + ((size_t)b * SEQ + (size_t)chunk * RPC) * UNITS + lane * 8;
    float* pout = out + (size_t)BATCH * UNITS + (size_t)b * SEQ + (size_t)chunk * RPC;

    // 4 rows in flight: rows r, r+4, r+8, r+12; wave stride 16 -> 8 iters
    for (int r = wave; r < RPC; r += 16) {
        const float* r0 = hb + (size_t)r * UNITS;
        const float* r1 = hb + (size_t)(r + 4) * UNITS;
        const float* r2 = hb + (size_t)(r + 8) * UNITS;
        const float* r3 = hb + (size_t)(r + 12) * UNITS;
        f4 a0 = *(const f4*)r0;
        f4 b0 = *(const f4*)(r0 + 4);
        f4 a1 = *(const f4*)r1;
        f4 b1 = *(const f4*)(r1 + 4);
        f4 a2 = *(const f4*)r2;
        f4 b2 = *(const f4*)(r2 + 4);
        f4 a3 = *(const f4*)r3;
        f4 b3 = *(const f4*)(r3 + 4);

        float d0 = dot8(a0, b0, u0, u1);
        float d1 = dot8(a1, b1, u0, u1);
        float d2 = dot8(a2, b2, u0, u1);
        float d3 = dot8(a3, b3, u0, u1);
#pragma unroll
        for (int off = 32; off >= 1; off >>= 1) {
            d0 += __shfl_xor(d0, off);
            d1 += __shfl_xor(d1, off);
            d2 += __shfl_xor(d2, off);
            d3 += __shfl_xor(d3, off);
        }
        float w0 = __expf(tanhf(d0 + pb));
        float w1 = __expf(tanhf(d1 + pb));
        float w2 = __expf(tanhf(d2 + pb));
        float w3 = __expf(tanhf(d3 + pb));
        if (lane == 0) {
            pout[r]      = w0;
            pout[r + 4]  = w1;
            pout[r + 8]  = w2;
            pout[r + 12] = w3;
        }
        zs += (w0 + w1) + (w2 + w3);
        acc0 += w0 * a0 + w1 * a1;
        acc0 += w2 * a2 + w3 * a3;
        acc1 += w0 * b0 + w1 * b1;
        acc1 += w2 * b2 + w3 * b3;
    }

    __shared__ float lctx[4][UNITS];
    __shared__ float lsum[4];
    *(f4*)&lctx[wave][lane * 8]     = acc0;
    *(f4*)&lctx[wave][lane * 8 + 4] = acc1;
    if (lane == 0) lsum[wave] = zs;
    __syncthreads();

    float* pc = ws + OFF_PCTX + ((size_t)(b * CHUNKS + chunk)) * UNITS;
    for (int col = tid; col < UNITS; col += 256)
        pc[col] = lctx[0][col] + lctx[1][col] + lctx[2][col] + lctx[3][col];
    if (tid == 0)
        ws[OFF_PSUM + b * CHUNKS + chunk] = lsum[0] + lsum[1] + lsum[2] + lsum[3];
}

// K2 (256 blocks): block = (b, slice). Z from psum (redundant per block),
// context slice of 64 cols, scale 512 weights in place.
__global__ __launch_bounds__(256) void k_final(const float* __restrict__ ws,
                                               float* __restrict__ out) {
    int blk = blockIdx.x;
    int b = blk >> 3, sl = blk & 7;
    int tid = threadIdx.x;

    __shared__ float zsh;
    if (tid < 64) {
        float z = (tid < CHUNKS) ? ws[OFF_PSUM + b * CHUNKS + tid] : 0.f;
        z = wave_reduce_add(z);
        if (tid == 0) zsh = 1.0f / z;
    }
    __syncthreads();
    float rz = zsh;

    int col = sl * 64 + (tid & 63);
    int grp = tid >> 6;
    float s = 0.f;
#pragma unroll
    for (int c = 0; c < 8; ++c)
        s += ws[OFF_PCTX + (size_t)(b * CHUNKS + grp * 8 + c) * UNITS + col];
    __shared__ float red[4][64];
    red[grp][tid & 63] = s;
    __syncthreads();
    if (tid < 64)
        out[(size_t)b * UNITS + sl * 64 + tid] =
            (red[0][tid] + red[1][tid] + red[2][tid] + red[3][tid]) * rz;

    float* wout = out + (size_t)BATCH * UNITS + (size_t)b * SEQ + sl * 512;
#pragma unroll
    for (int i = tid; i < 512; i += 256) wout[i] *= rz;
}

extern "C" void kernel_launch(void* const* d_in, const int* in_sizes, int n_in,
                              void* d_out, int out_size, void* d_ws, size_t ws_size,
                              hipStream_t stream) {
    (void)in_sizes; (void)n_in; (void)out_size; (void)ws_size;
    const float* s_prev = (const float*)d_in[0];
    const float* h      = (const float*)d_in[1];
    const float* Ww     = (const float*)d_in[2];
    const float* Wb     = (const float*)d_in[3];
    const float* Uw     = (const float*)d_in[4];
    const float* Ub     = (const float*)d_in[5];
    const float* Vw     = (const float*)d_in[6];
    const float* Vb     = (const float*)d_in[7];
    float* out = (float*)d_out;
    float* ws  = (float*)d_ws;

    hipLaunchKernelGGL(k_prep,  dim3(PREPB),         dim3(256), 0, stream,
                       Ww, Uw, Vw, Wb, Ub, Vb, s_prev, ws);
    hipLaunchKernelGGL(k_main,  dim3(CHUNKS, BATCH), dim3(256), 0, stream,
                       h, ws, out);
    hipLaunchKernelGGL(k_final, dim3(256),           dim3(256), 0, stream,
                       ws, out);
}

// Round 6
// 54.525 us; speedup vs baseline: 1.1995x; 1.0015x over previous
//
#include <hip/hip_runtime.h>
#include <math.h>

#define UNITS  512
#define BATCH  32
#define SEQ    4096
#define CHUNKS 64
#define RPC    (SEQ / CHUNKS)   // 64 rows per chunk
#define PREPB  64               // k_prep blocks; pp partials per batch

// workspace layout (float offsets)
#define OFF_UV    0                       // 512
#define OFF_WV    512                     // 512
#define OFF_PP    1024                    // pp[b*PREPB+blk]  (32 x 64)
#define OFF_CB    3072                    // 1 scalar
#define OFF_PSUM  4096                    // BATCH*CHUNKS = 2048
#define OFF_PCTX  8192                    // BATCH*CHUNKS*UNITS = 1048576 (~4 MB)

typedef float f4 __attribute__((ext_vector_type(4)));

__device__ inline float wave_reduce_add(float v) {
#pragma unroll
    for (int off = 32; off >= 1; off >>= 1) v += __shfl_xor(v, off);
    return v;
}

__device__ inline float dot8(f4 a, f4 b, f4 u0, f4 u1) {
    f4 t = a * u0 + b * u1;
    return t.x + t.y + t.z + t.w;
}

// K0 (PREPB blocks x 8 rows): uv/wv rows, cb scalar, pbias partials.
__global__ __launch_bounds__(256) void k_prep(const float* __restrict__ Ww,
                                              const float* __restrict__ Uw,
                                              const float* __restrict__ Vw,
                                              const float* __restrict__ Wb,
                                              const float* __restrict__ Ub,
                                              const float* __restrict__ Vb,
                                              const float* __restrict__ s_prev,
                                              float* __restrict__ ws) {
    int tid = threadIdx.x, wave = tid >> 6, lane = tid & 63;
    f4 v0 = *(const f4*)(Vw + lane * 8);
    f4 v1 = *(const f4*)(Vw + lane * 8 + 4);
    int rowbase = blockIdx.x * 8;

    for (int i = wave; i < 8; i += 4) {
        int u = rowbase + i;
        const float* ur = Uw + (size_t)u * UNITS + lane * 8;
        f4 a = *(const f4*)ur;
        f4 b = *(const f4*)(ur + 4);
        float d = wave_reduce_add(dot8(a, b, v0, v1));
        if (lane == 0) ws[OFF_UV + u] = d;
        const float* wr = Ww + (size_t)u * UNITS + lane * 8;
        a = *(const f4*)wr;
        b = *(const f4*)(wr + 4);
        d = wave_reduce_add(dot8(a, b, v0, v1));
        if (lane == 0) ws[OFF_WV + u] = d;
    }

    if (blockIdx.x == 0) {
        float part = 0.f;
        for (int v = tid; v < UNITS; v += 256) part += (Wb[v] + Ub[v]) * Vw[v];
        part = wave_reduce_add(part);
        __shared__ float wred[4];
        if (lane == 0) wred[wave] = part;
        __syncthreads();
        if (tid == 0) ws[OFF_CB] = wred[0] + wred[1] + wred[2] + wred[3] + Vb[0];
    }

    __syncthreads();  // this block's wv rows visible block-wide

    // pp[b][blk] = sum_{j=0..7} s_prev[b, rowbase+j] * wv[rowbase+j]
    int b = tid >> 3;      // 0..31
    int g = tid & 7;       // 0..7
    int u = rowbase + g;
    float p = s_prev[(size_t)b * UNITS + u] * ws[OFF_WV + u];
    p += __shfl_xor(p, 1);
    p += __shfl_xor(p, 2);
    p += __shfl_xor(p, 4);
    if (g == 0) ws[OFF_PP + b * PREPB + blockIdx.x] = p;
}

// K1 (64x32 blocks): stream h once, 4 rows in flight per wave.
// p=exp(tanh(h.uv+pb)) unnormalized to output weights region; partial Z
// and context to ws.
__global__ __launch_bounds__(256) void k_main(const float* __restrict__ h,
                                              float* __restrict__ ws,
                                              float* __restrict__ out) {
    int chunk = blockIdx.x, b = blockIdx.y;
    int tid = threadIdx.x, wave = tid >> 6, lane = tid & 63;

    __shared__ float pbsh;
    {
        float p = ws[OFF_PP + b * PREPB + lane];   // PREPB == 64 lanes
        p = wave_reduce_add(p);
        if (tid == 0) pbsh = p + ws[OFF_CB];
    }
    f4 u0 = *(const f4*)(ws + OFF_UV + lane * 8);
    f4 u1 = *(const f4*)(ws + OFF_UV + lane * 8 + 4);
    __syncthreads();
    float pb = pbsh;

    f4 acc0 = {0.f, 0.f, 0.f, 0.f};
    f4 acc1 = {0.f, 0.f, 0.f, 0.f};
    float zs = 0.f;

    const float* hb = h + ((size_t)b * SEQ + (size_t)chunk * RPC) * UNITS + lane * 8;
    float* pout = out + (size_t)BATCH * UNITS + (size_t)b * SEQ + (size_t)chunk * RPC;

    // 4 rows in flight: rows r, r+4, r+8, r+12; wave stride 16 -> 4 iters
    for (int r = wave; r < RPC; r += 16) {
        const float* r0 = hb + (size_t)r * UNITS;
        const float* r1 = hb + (size_t)(r + 4) * UNITS;
        const float* r2 = hb + (size_t)(r + 8) * UNITS;
        const float* r3 = hb + (size_t)(r + 12) * UNITS;
        f4 a0 = *(const f4*)r0;
        f4 b0 = *(const f4*)(r0 + 4);
        f4 a1 = *(const f4*)r1;
        f4 b1 = *(const f4*)(r1 + 4);
        f4 a2 = *(const f4*)r2;
        f4 b2 = *(const f4*)(r2 + 4);
        f4 a3 = *(const f4*)r3;
        f4 b3 = *(const f4*)(r3 + 4);

        float d0 = dot8(a0, b0, u0, u1);
        float d1 = dot8(a1, b1, u0, u1);
        float d2 = dot8(a2, b2, u0, u1);
        float d3 = dot8(a3, b3, u0, u1);
#pragma unroll
        for (int off = 32; off >= 1; off >>= 1) {
            d0 += __shfl_xor(d0, off);
            d1 += __shfl_xor(d1, off);
            d2 += __shfl_xor(d2, off);
            d3 += __shfl_xor(d3, off);
        }
        float w0 = __expf(tanhf(d0 + pb));
        float w1 = __expf(tanhf(d1 + pb));
        float w2 = __expf(tanhf(d2 + pb));
        float w3 = __expf(tanhf(d3 + pb));
        if (lane == 0) {
            pout[r]      = w0;
            pout[r + 4]  = w1;
            pout[r + 8]  = w2;
            pout[r + 12] = w3;
        }
        zs += (w0 + w1) + (w2 + w3);
        acc0 += w0 * a0 + w1 * a1;
        acc0 += w2 * a2 + w3 * a3;
        acc1 += w0 * b0 + w1 * b1;
        acc1 += w2 * b2 + w3 * b3;
    }

    __shared__ float lctx[4][UNITS];
    __shared__ float lsum[4];
    *(f4*)&lctx[wave][lane * 8]     = acc0;
    *(f4*)&lctx[wave][lane * 8 + 4] = acc1;
    if (lane == 0) lsum[wave] = zs;
    __syncthreads();

    float* pc = ws + OFF_PCTX + ((size_t)(b * CHUNKS + chunk)) * UNITS;
    for (int col = tid; col < UNITS; col += 256)
        pc[col] = lctx[0][col] + lctx[1][col] + lctx[2][col] + lctx[3][col];
    if (tid == 0)
        ws[OFF_PSUM + b * CHUNKS + chunk] = lsum[0] + lsum[1] + lsum[2] + lsum[3];
}

// K2 (256 blocks): block = (b, slice). Z from psum (redundant per block),
// context slice of 64 cols, scale 512 weights in place.
__global__ __launch_bounds__(256) void k_final(const float* __restrict__ ws,
                                               float* __restrict__ out) {
    int blk = blockIdx.x;
    int b = blk >> 3, sl = blk & 7;
    int tid = threadIdx.x;

    __shared__ float zsh;
    if (tid < 64) {
        float z = ws[OFF_PSUM + b * CHUNKS + tid];   // CHUNKS == 64 lanes
        z = wave_reduce_add(z);
        if (tid == 0) zsh = 1.0f / z;
    }
    __syncthreads();
    float rz = zsh;

    int col = sl * 64 + (tid & 63);
    int grp = tid >> 6;
    float s = 0.f;
#pragma unroll
    for (int c = 0; c < 16; ++c)
        s += ws[OFF_PCTX + (size_t)(b * CHUNKS + grp * 16 + c) * UNITS + col];
    __shared__ float red[4][64];
    red[grp][tid & 63] = s;
    __syncthreads();
    if (tid < 64)
        out[(size_t)b * UNITS + sl * 64 + tid] =
            (red[0][tid] + red[1][tid] + red[2][tid] + red[3][tid]) * rz;

    float* wout = out + (size_t)BATCH * UNITS + (size_t)b * SEQ + sl * 512;
#pragma unroll
    for (int i = tid; i < 512; i += 256) wout[i] *= rz;
}

extern "C" void kernel_launch(void* const* d_in, const int* in_sizes, int n_in,
                              void* d_out, int out_size, void* d_ws, size_t ws_size,
                              hipStream_t stream) {
    (void)in_sizes; (void)n_in; (void)out_size; (void)ws_size;
    const float* s_prev = (const float*)d_in[0];
    const float* h      = (const float*)d_in[1];
    const float* Ww     = (const float*)d_in[2];
    const float* Wb     = (const float*)d_in[3];
    const float* Uw     = (const float*)d_in[4];
    const float* Ub     = (const float*)d_in[5];
    const float* Vw     = (const float*)d_in[6];
    const float* Vb     = (const float*)d_in[7];
    float* out = (float*)d_out;
    float* ws  = (float*)d_ws;

    hipLaunchKernelGGL(k_prep,  dim3(PREPB),         dim3(256), 0, stream,
                       Ww, Uw, Vw, Wb, Ub, Vb, s_prev, ws);
    hipLaunchKernelGGL(k_main,  dim3(CHUNKS, BATCH), dim3(256), 0, stream,
                       h, ws, out);
    hipLaunchKernelGGL(k_final, dim3(256),           dim3(256), 0, stream,
                       ws, out);
}